// Round 1
// baseline (122.979 us; speedup 1.0000x reference)
//
#include <hip/hip_runtime.h>

// LengthRegulator: expanded[b,pos,:] = encoder_out[b, searchsorted(cum_dur[b], pos, 'right'), :]
// for pos < min(mel_len, max_len), else 0; mel_lens[b] = cum_dur[b, T-1].
//
// Shapes fixed by the reference: B=16, T=512, D=384; max_len derived from out_size.
// d_out layout: [B*max_len*D floats expanded][B floats mel_lens].

#define LR_B       16
#define LR_T       512
#define LR_D4      96          // D/4 float4s per frame (D=384)
#define LR_FRAMES  64          // output frames per block
#define LR_THREADS 512

__global__ __launch_bounds__(LR_THREADS)
void lr_expand_kernel(const float4* __restrict__ enc,   // [B*T*D4] float4
                      const int*    __restrict__ dur,   // [B*T]
                      float*        __restrict__ out,   // [B*max_len*D + B]
                      int max_len) {
    const int b    = blockIdx.y;
    const int pos0 = blockIdx.x * LR_FRAMES;
    const int tid  = threadIdx.x;

    __shared__ int s_cum[LR_T];
    __shared__ int s_tok[LR_FRAMES];

    // ---- load durations row + inclusive scan (Hillis-Steele, 512 elems) ----
    s_cum[tid] = dur[b * LR_T + tid];
    __syncthreads();
#pragma unroll
    for (int off = 1; off < LR_T; off <<= 1) {
        int v = (tid >= off) ? s_cum[tid - off] : 0;
        __syncthreads();
        s_cum[tid] += v;
        __syncthreads();
    }

    const int mel_raw = s_cum[LR_T - 1];
    const int mel     = min(mel_raw, max_len);

    // mel_lens tail (written once per batch, by the chunk-0 block)
    if (blockIdx.x == 0 && tid == 0) {
        out[(size_t)LR_B * max_len * (LR_D4 * 4) + b] = (float)mel_raw;
    }

    // ---- per-frame token index: upper_bound(cum, pos), clipped to T-1 ----
    if (tid < LR_FRAMES) {
        int pos = pos0 + tid;
        int lo = 0, hi = LR_T;
        while (lo < hi) {
            int mid = (lo + hi) >> 1;
            if (s_cum[mid] <= pos) lo = mid + 1; else hi = mid;
        }
        s_tok[tid] = min(lo, LR_T - 1);
    }
    __syncthreads();

    // ---- copy phase: LR_FRAMES frames x LR_D4 float4, coalesced ----
    float4* out4 = (float4*)out;
    const size_t out_base = ((size_t)b * max_len + pos0) * LR_D4;
    const float4 zero4 = make_float4(0.f, 0.f, 0.f, 0.f);
#pragma unroll
    for (int it = 0; it < (LR_FRAMES * LR_D4) / LR_THREADS; ++it) {
        int j   = it * LR_THREADS + tid;
        int f   = j / LR_D4;
        int d4  = j - f * LR_D4;
        int pos = pos0 + f;
        if (pos >= max_len) continue;   // guard for non-multiple max_len (never hit at 4096)
        float4 val = zero4;
        if (pos < mel) {
            val = enc[(size_t)(b * LR_T + s_tok[f]) * LR_D4 + d4];
        }
        out4[out_base + (size_t)f * LR_D4 + d4] = val;
    }
}

extern "C" void kernel_launch(void* const* d_in, const int* in_sizes, int n_in,
                              void* d_out, int out_size, void* d_ws, size_t ws_size,
                              hipStream_t stream) {
    const float4* enc = (const float4*)d_in[0];   // encoder_out f32 [B,T,D]
    const int*    dur = (const int*)d_in[1];      // durations i32 [B,T]
    float*        out = (float*)d_out;

    // out_size = B*max_len*D + B  ->  max_len
    const int max_len = (out_size - LR_B) / (LR_B * LR_D4 * 4);

    dim3 grid((max_len + LR_FRAMES - 1) / LR_FRAMES, LR_B);
    lr_expand_kernel<<<grid, LR_THREADS, 0, stream>>>(enc, dur, out, max_len);
}